// Round 3
// baseline (236.558 us; speedup 1.0000x reference)
//
#include <hip/hip_runtime.h>
#include <math.h>

// LIF recurrence: v = v + (x_t - v)/tau; s = sigmoid(v - th); v *= (1 - s)
// x: [B=32, T=512, D=2048] fp32 -> spikes s, same shape.
//
// R1/R2 lesson: one thread per chain = 1024 waves = 1 wave/SIMD -> zero TLP,
// latency-bound at ~2.7 GB/s/wave no matter how the loads are pipelined.
//
// Fix: the recurrence is contractive. v' = g(v + (x-v)/2), g(u)=u*(1-sigmoid(u-1)),
// |g'(u)| <= 1.045 (peak near u=-2) -> per-step Jacobian <= 0.5*1.045 = 0.53.
// So split T=512 into 8 segments of 64; each segment's thread starts v=0 but
// runs 16 discarded warmup steps first: error ~2 * 0.53^16 * sigma'(<=0.25)
// ~ 1e-5, far below the 1.7e-2 pass threshold.
// => 8x parallelism (2048 blocks, 8 waves/SIMD = full residency) for 25% extra
// reads (warmup re-reads are L3-warm: the neighbor segment just fetched them).

#define TAU_INV 0.5f
#define TH 1.0f

constexpr int BATCH = 32;
constexpr int TT = 512;
constexpr int DD = 2048;
constexpr int SEG = 8;            // segments per chain
constexpr int SEGLEN = TT / SEG;  // 64 output steps per thread
constexpr int WARM = 16;          // discarded warmup steps (err ~0.53^16)
constexpr int U = 8;              // time steps per load batch

__global__ __launch_bounds__(256, 8) void lif_kernel(const float* __restrict__ x,
                                                     float* __restrict__ out) {
    int tid = blockIdx.x * blockDim.x + threadIdx.x;   // [0, B*D*SEG)
    int d   = tid & (DD - 1);                          // lanes = consecutive d
    int b   = (tid >> 11) & (BATCH - 1);
    int seg = tid >> 16;                               // 0..7
    const size_t base = (size_t)b * TT * DD + d;
    const float* xp = x + base;
    float* op = out + base;
    const int t0 = seg * SEGLEN;

    float v = 0.0f;

    // Warmup: converge v from 0 using the 16 steps before this segment.
    // Cached (non-NT) loads: this region was just read by segment seg-1.
    if (seg > 0) {
        const float* xw = xp + (size_t)(t0 - WARM) * DD;
        #pragma unroll
        for (int w0 = 0; w0 < WARM; w0 += U) {
            float xs[U];
            #pragma unroll
            for (int i = 0; i < U; ++i)
                xs[i] = xw[(size_t)(w0 + i) * DD];
            #pragma unroll
            for (int i = 0; i < U; ++i) {
                v = v + (xs[i] - v) * TAU_INV;
                float s = 1.0f / (1.0f + __expf(TH - v));
                v = v * (1.0f - s);
            }
        }
    }

    // Main: 64 steps, double-buffered batches of 8, NT stores (never re-read).
    const float* xm = xp + (size_t)t0 * DD;
    float* om = op + (size_t)t0 * DD;
    float buf[2][U];
    #pragma unroll
    for (int i = 0; i < U; ++i)
        buf[0][i] = xm[(size_t)i * DD];

    constexpr int NB = SEGLEN / U;  // 8 stages
    #pragma unroll
    for (int blk = 0; blk < NB; ++blk) {
        const int cur = blk & 1, nxt = cur ^ 1;
        if (blk + 1 < NB) {
            const float* xn = xm + (size_t)(blk + 1) * U * DD;
            #pragma unroll
            for (int i = 0; i < U; ++i)
                buf[nxt][i] = xn[(size_t)i * DD];
        }
        float* ob = om + (size_t)blk * U * DD;
        #pragma unroll
        for (int i = 0; i < U; ++i) {
            v = v + (buf[cur][i] - v) * TAU_INV;         // leak/integrate
            float s = 1.0f / (1.0f + __expf(TH - v));    // sigmoid(v - th)
            __builtin_nontemporal_store(s, ob + (size_t)i * DD);
            v = v * (1.0f - s);                           // soft reset
        }
    }
}

extern "C" void kernel_launch(void* const* d_in, const int* in_sizes, int n_in,
                              void* d_out, int out_size, void* d_ws, size_t ws_size,
                              hipStream_t stream) {
    const float* x = (const float*)d_in[0];
    float* out = (float*)d_out;
    const int threads = 256;
    const int total = BATCH * DD * SEG;                  // 524288 threads
    const int blocks = (total + threads - 1) / threads;  // 2048
    lif_kernel<<<blocks, threads, 0, stream>>>(x, out);
}

// Round 4
// 233.658 us; speedup vs baseline: 1.0124x; 1.0124x over previous
//
#include <hip/hip_runtime.h>
#include <math.h>

// LIF recurrence: v = v + (x_t - v)/tau; s = sigmoid(v - th); v *= (1 - s)
// x: [B=32, T=512, D=2048] fp32 -> spikes s, same shape.
//
// R1/R3 lesson: BW pinned at 2.5 TB/s at BOTH 1 and 8 waves/SIMD -> not
// latency/occupancy. Diagnosis: channel aliasing. All chains walk t in
// lockstep; active addresses b*4MB + (64s+p)*8KB alias mod any power-of-2
// channel-interleave period (b*4MB == 0, 64s*8KB == 0) -> the whole machine
// hammers ~one plane's worth of HBM channels/L3 slices at any instant.
//
// Fix: stagger segment phase by b. Segment s of chain (b,d) covers
// [64s+b, 64(s+1)+b) (clamped to [0,512)). Instantaneous t-set becomes
// {64s+p+b}: 256 distinct planes -> all channels covered for any
// power-of-2 interleave granularity 256B..4KB.
//
// Warmup correctness: recurrence is contractive, per-step Jacobian
// <= 0.5*1.045 = 0.53; 16 discarded warmup steps -> state error ~1e-5,
// far under the 1.7e-2 threshold (R3 absmax matched exact-version's).

#define TAU_INV 0.5f
#define TH 1.0f

constexpr int BATCH = 32;
constexpr int TT = 512;
constexpr int DD = 2048;
constexpr int SEG = 8;
constexpr int SEGLEN = TT / SEG;  // 64
constexpr int WARM = 16;
constexpr int U = 8;              // time steps per pipeline stage

__global__ __launch_bounds__(256, 8) void lif_kernel(const float* __restrict__ x,
                                                     float* __restrict__ out) {
    int tid = blockIdx.x * blockDim.x + threadIdx.x;   // [0, B*D*SEG)
    int d   = tid & (DD - 1);                          // lanes = consecutive d
    int b   = (tid >> 11) & (BATCH - 1);
    int seg = tid >> 16;                               // 0..7
    const size_t base = (size_t)b * TT * DD + d;
    const float* xp = x + base;
    float* op = out + base;

    const int phi     = b;                                       // 0..31 stagger
    const int t_start = (seg == 0) ? 0 : seg * SEGLEN + phi;
    const int t_end   = (seg == SEG - 1) ? TT : (seg + 1) * SEGLEN + phi;

    float v = 0.0f;

    // Warmup: converge v from 0 over the 16 steps before t_start (discarded).
    if (seg > 0) {
        const float* xw = xp + (size_t)(t_start - WARM) * DD;
        #pragma unroll
        for (int w0 = 0; w0 < WARM; w0 += U) {
            float xs[U];
            #pragma unroll
            for (int i = 0; i < U; ++i)
                xs[i] = xw[(size_t)(w0 + i) * DD];
            #pragma unroll
            for (int i = 0; i < U; ++i) {
                v = v + (xs[i] - v) * TAU_INV;
                float s = 1.0f / (1.0f + __expf(TH - v));
                v = v * (1.0f - s);
            }
        }
    }

    // Main: dynamic length (33..95 steps), double-buffered batches of U=8.
    // Explicit ping-pong stages (macro) keep buf[] register-resident.
    const int len = t_end - t_start;
    const int nb  = (len + U - 1) / U;

    float buf0[U], buf1[U];

    // Prologue: stage 0 loads (t_start+7 <= 486 < 512, always in-bounds).
    #pragma unroll
    for (int i = 0; i < U; ++i)
        buf0[i] = __builtin_nontemporal_load(xp + (size_t)(t_start + i) * DD);

#define STAGE(CUR, NXT)                                                        \
    {                                                                          \
        const int tb = t_start + (blk + 1) * U;                                \
        if (blk + 1 < nb) {                                                    \
            _Pragma("unroll")                                                  \
            for (int i = 0; i < U; ++i) {                                      \
                int t = tb + i;                                                \
                if (t >= TT) t = TT - 1; /* clamp: only seg 7 can overrun */   \
                NXT[i] = __builtin_nontemporal_load(xp + (size_t)t * DD);      \
            }                                                                  \
        }                                                                      \
        const int ts = t_start + blk * U;                                      \
        _Pragma("unroll")                                                      \
        for (int i = 0; i < U; ++i) {                                          \
            v = v + (CUR[i] - v) * TAU_INV;                                    \
            float s = 1.0f / (1.0f + __expf(TH - v));                          \
            if (ts + i < t_end)                                                \
                __builtin_nontemporal_store(s, op + (size_t)(ts + i) * DD);    \
            v = v * (1.0f - s);                                                \
        }                                                                      \
    }

    int blk = 0;
    while (true) {
        STAGE(buf0, buf1)
        if (++blk == nb) break;
        STAGE(buf1, buf0)
        if (++blk == nb) break;
    }
#undef STAGE
}

extern "C" void kernel_launch(void* const* d_in, const int* in_sizes, int n_in,
                              void* d_out, int out_size, void* d_ws, size_t ws_size,
                              hipStream_t stream) {
    const float* x = (const float*)d_in[0];
    float* out = (float*)d_out;
    const int threads = 256;
    const int total = BATCH * DD * SEG;                  // 524288 threads
    const int blocks = (total + threads - 1) / threads;  // 2048
    lif_kernel<<<blocks, threads, 0, stream>>>(x, out);
}